// Round 13
// baseline (486.952 us; speedup 1.0000x reference)
//
#include <hip/hip_runtime.h>
#include <hip/hip_bf16.h>

#define THREADS 256
#define NN 100000
#define EE 1600000
#define ETT (EE + NN)

// ===== VERIFIED OUTPUT MODEL: d_out is FLOAT32, 16M f32 els =====
//   out : f32 els [0, 12.8M)    ei : f32 els [12.8M, 16M)
#define EI_F32  12800000u
// Scratch tiers (host-picked):
//   A: ws>=46MB : d_ws, st=16 (64B/node atomic padding), bf16-x copy
//   B: ws>=34MB : d_ws, st=1, bf16-x copy
//   C: else     : d_out ei-region (12.8MB), st=1, no x copy (stomped by copy_ei)

__device__ __forceinline__ unsigned short f2bf(float f) {
  unsigned u = __float_as_uint(f);
  u = u + 0x7FFFu + ((u >> 16) & 1u);   // RNE
  return (unsigned short)(u >> 16);
}
__device__ __forceinline__ float bf2f(unsigned short v) {
  return __uint_as_float((unsigned)v << 16);
}
__device__ __forceinline__ float lrelu(float a) { return a > 0.f ? a : 0.2f * a; }

// edge_index element fetch: mode 0=int32, 1=int64(low word), 2=fp32
__device__ __forceinline__ int load_edge(const void* ei, int mode, int idx) {
  int v;
  if (mode == 1)      v = ((const int*)ei)[2 * (size_t)idx];
  else if (mode == 2) v = (int)(((const float*)ei)[idx]);
  else                v = ((const int*)ei)[idx];
  return ((unsigned)v < NN) ? v : 0;
}

// ---- setup: zero degcur/denom (strided); block 0: detect + g/c precompute --
__global__ void k_setup(const unsigned* __restrict__ ei_u,
                        const float* __restrict__ c0, const float* __restrict__ c1,
                        const float* __restrict__ W,
                        int* __restrict__ hdr, float* __restrict__ gc,
                        unsigned* __restrict__ degcur, float* __restrict__ denom,
                        int st) {
  int i = blockIdx.x * THREADS + threadIdx.x;
  if (i < NN) { degcur[(size_t)i * st] = 0u; denom[(size_t)i * st] = 0.f; }
  if (blockIdx.x != 0) return;
  __shared__ int sbias;
  int t = threadIdx.x;
  if (t < 64) {
    int odd_nz = 0, even_big = 0;
    for (int k = t; k < 2048; k += 64) {
      unsigned w = ei_u[k];
      if (k & 1) odd_nz += (w != 0u);
      else       even_big += (w >= 1000000u);
    }
    #pragma unroll
    for (int m = 1; m < 64; m <<= 1) {
      odd_nz += __shfl_xor(odd_nz, m, 64);
      even_big += __shfl_xor(even_big, m, 64);
    }
    const unsigned* u0 = (const unsigned*)c0;
    const unsigned* u1 = (const unsigned*)c1;
    unsigned s0 = u0[t] | u0[t + 64], s1 = u1[t] | u1[t + 64];
    #pragma unroll
    for (int m = 1; m < 64; m <<= 1) {
      s0 |= __shfl_xor(s0, m, 64);
      s1 |= __shfl_xor(s1, m, 64);
    }
    if (t == 0) {
      hdr[0] = (odd_nz == 0) ? 1 : ((even_big > 512) ? 2 : 0);
      int b = (s0 == 0u) ? 1 : ((s1 == 0u) ? 0 : 1);
      hdr[1] = b;
      sbias = b;
    }
  }
  __syncthreads();
  const float* bias = sbias ? c0 : c1;
  const float* att  = sbias ? c1 : c0;
  if (t < 128) {
    float g = 0.f;
    for (int o = 0; o < 128; ++o) g = fmaf(att[o], W[o * 128 + t], g);
    gc[t] = g;
    if (t == 0) {
      float c = 0.f;
      for (int o = 0; o < 128; ++o) c = fmaf(att[o], bias[o], c);
      gc[128] = c;
    }
  }
}

// ---- s[i] = bf16(x[i].g + c); optional bf16 copy of x ----------------------
__global__ __launch_bounds__(THREADS) void k_sq(const float* __restrict__ x,
                                                const float* __restrict__ gc,
                                                unsigned short* __restrict__ s,
                                                unsigned short* __restrict__ xb,
                                                int wantxb) {
  int node = blockIdx.x * 4 + (threadIdx.x >> 6);
  if (node >= NN) return;
  int l = threadIdx.x & 63;
  float2 xv = *(const float2*)&x[(size_t)node * 128 + l * 2];
  if (wantxb) {
    unsigned pk = (unsigned)f2bf(xv.x) | ((unsigned)f2bf(xv.y) << 16);
    *(unsigned*)&xb[(size_t)node * 128 + l * 2] = pk;
  }
  float2 gv = *(const float2*)&gc[l * 2];
  float v = xv.x * gv.x + xv.y * gv.y;
  #pragma unroll
  for (int m = 1; m < 64; m <<= 1) v += __shfl_xor(v, m, 64);
  if (l == 0) s[node] = f2bf(v + gc[128]);
}

// ---- edge pass 1: denom += exp(alpha) (by src, incl. self); deg (by dst) ---
__global__ void k_edge1(const void* __restrict__ ei, const int* __restrict__ hdr,
                        const unsigned short* __restrict__ s,
                        unsigned* __restrict__ degcur, float* __restrict__ denom,
                        int st) {
  int e = blockIdx.x * THREADS + threadIdx.x;
  if (e >= ETT) return;
  int mode = hdr[0];
  if (e < EE) {
    int src = load_edge(ei, mode, e);
    int dst = load_edge(ei, mode, EE + e);
    float a = lrelu(bf2f(s[dst]) + bf2f(s[src]));
    atomicAdd(&denom[(size_t)src * st], __expf(fminf(a, 60.f)));
    atomicAdd(&degcur[(size_t)dst * st], 1u);
  } else {
    int i = e - EE;
    float a = lrelu(2.f * bf2f(s[i]));
    atomicAdd(&denom[(size_t)i * st], __expf(fminf(a, 60.f)));
  }
}

// ---- prefix scan of degcur -> in-place exclusive (strided) -----------------
__global__ void k_part(const unsigned* __restrict__ degcur, unsigned* __restrict__ part,
                       int st) {
  int i = blockIdx.x * THREADS + threadIdx.x;
  unsigned v = (i < NN) ? degcur[(size_t)i * st] : 0u;
  #pragma unroll
  for (int m = 1; m < 64; m <<= 1) v += __shfl_xor(v, m, 64);
  __shared__ unsigned sm[4];
  if ((threadIdx.x & 63) == 0) sm[threadIdx.x >> 6] = v;
  __syncthreads();
  if (threadIdx.x == 0) part[blockIdx.x] = sm[0] + sm[1] + sm[2] + sm[3];
}

__global__ void k_scan_top(unsigned* __restrict__ part, int nb) {  // 1 block, 512 thr
  int t = threadIdx.x;
  int lane = t & 63, w = t >> 6;
  unsigned v = (t < nb) ? part[t] : 0u;
  unsigned inc = v;
  #pragma unroll
  for (int d = 1; d < 64; d <<= 1) {
    unsigned o = __shfl_up(inc, d, 64);
    if (lane >= d) inc += o;
  }
  __shared__ unsigned wsum[8];
  if (lane == 63) wsum[w] = inc;
  __syncthreads();
  unsigned off = 0;
  for (int j = 0; j < w; ++j) off += wsum[j];
  if (t < nb) part[t] = inc - v + off;  // exclusive
}

__global__ void k_scan_final(unsigned* __restrict__ degcur, const unsigned* __restrict__ part,
                             int st) {
  int i = blockIdx.x * THREADS + threadIdx.x;
  int lane = threadIdx.x & 63, w = threadIdx.x >> 6;
  unsigned v = (i < NN) ? degcur[(size_t)i * st] : 0u;
  unsigned inc = v;
  #pragma unroll
  for (int d = 1; d < 64; d <<= 1) {
    unsigned o = __shfl_up(inc, d, 64);
    if (lane >= d) inc += o;
  }
  __shared__ unsigned wsum[4];
  if (lane == 63) wsum[w] = inc;
  __syncthreads();
  unsigned off = part[blockIdx.x];
  for (int j = 0; j < w; ++j) off += wsum[j];
  if (i < NN) degcur[(size_t)i * st] = inc - v + off;   // in-place exclusive
}

// ---- edge pass 2: minimal CSR fill (src only) by dst -----------------------
__global__ void k_edge2(const void* __restrict__ ei, const int* __restrict__ hdr,
                        unsigned* __restrict__ degcur, unsigned* __restrict__ ent_src,
                        int st) {
  int e = blockIdx.x * THREADS + threadIdx.x;
  if (e >= EE) return;
  int mode = hdr[0];
  int src = load_edge(ei, mode, e);
  int dst = load_edge(ei, mode, EE + e);
  unsigned pos = atomicAdd(&degcur[(size_t)dst * st], 1u);
  if (pos < (unsigned)EE) ent_src[pos] = (unsigned)src;
}

// ---- aggregation v4: stage (src, w) lane-parallel; unroll-4 row gathers ----
// w computed here: w = exp(lrelu(s_v + s[src]))/denom[src]; sumw -> own array.
template<int XB>
__global__ __launch_bounds__(THREADS) void k_agg(
    const unsigned* __restrict__ degcur, const unsigned* __restrict__ ent_src,
    const float* __restrict__ denom, const unsigned short* __restrict__ s,
    unsigned short* __restrict__ sumw_out,
    const float* __restrict__ x, const unsigned short* __restrict__ xb,
    float* __restrict__ z, int st) {
  int v = blockIdx.x * 4 + (threadIdx.x >> 6);
  if (v >= NN) return;
  int l = threadIdx.x & 63;
  unsigned beg = v ? degcur[(size_t)(v - 1) * st] : 0u;
  unsigned end = degcur[(size_t)v * st];
  float sv = bf2f(s[v]);
  float wself = __expf(fminf(lrelu(2.f * sv), 60.f)) / denom[(size_t)v * st];
  float z0, z1, wsum = wself;
  if (XB) {
    unsigned hv = *(const unsigned*)&xb[((size_t)v << 7) + (l << 1)];
    z0 = wself * bf2f((unsigned short)(hv & 0xFFFFu));
    z1 = wself * bf2f((unsigned short)(hv >> 16));
  } else {
    float2 xv = *(const float2*)&x[((size_t)v << 7) + (l << 1)];
    z0 = wself * xv.x; z1 = wself * xv.y;
  }

  for (unsigned j0 = beg; j0 < end; j0 += 64) {
    unsigned n = end - j0; if (n > 64u) n = 64u;
    unsigned msrc = 0u; float mw = 0.f;
    if (l < (int)n) {                       // lane-parallel stage: src + w
      msrc = ent_src[j0 + l];
      float a = lrelu(sv + bf2f(s[msrc]));
      mw = __expf(fminf(a, 60.f)) / denom[(size_t)msrc * st];
    }
    int k = 0;
    for (; k + 4 <= (int)n; k += 4) {       // 4 independent gathers in flight
      unsigned sA = __shfl(msrc, k);     float wA = __shfl(mw, k);
      unsigned sB = __shfl(msrc, k + 1); float wB = __shfl(mw, k + 1);
      unsigned sC = __shfl(msrc, k + 2); float wC = __shfl(mw, k + 2);
      unsigned sD = __shfl(msrc, k + 3); float wD = __shfl(mw, k + 3);
      if (XB) {
        unsigned hA = *(const unsigned*)&xb[((size_t)sA << 7) + (l << 1)];
        unsigned hB = *(const unsigned*)&xb[((size_t)sB << 7) + (l << 1)];
        unsigned hC = *(const unsigned*)&xb[((size_t)sC << 7) + (l << 1)];
        unsigned hD = *(const unsigned*)&xb[((size_t)sD << 7) + (l << 1)];
        z0 = fmaf(wA, bf2f((unsigned short)(hA & 0xFFFFu)), z0);
        z1 = fmaf(wA, bf2f((unsigned short)(hA >> 16)), z1);
        z0 = fmaf(wB, bf2f((unsigned short)(hB & 0xFFFFu)), z0);
        z1 = fmaf(wB, bf2f((unsigned short)(hB >> 16)), z1);
        z0 = fmaf(wC, bf2f((unsigned short)(hC & 0xFFFFu)), z0);
        z1 = fmaf(wC, bf2f((unsigned short)(hC >> 16)), z1);
        z0 = fmaf(wD, bf2f((unsigned short)(hD & 0xFFFFu)), z0);
        z1 = fmaf(wD, bf2f((unsigned short)(hD >> 16)), z1);
      } else {
        float2 xA = *(const float2*)&x[((size_t)sA << 7) + (l << 1)];
        float2 xB_ = *(const float2*)&x[((size_t)sB << 7) + (l << 1)];
        float2 xC = *(const float2*)&x[((size_t)sC << 7) + (l << 1)];
        float2 xD = *(const float2*)&x[((size_t)sD << 7) + (l << 1)];
        z0 = fmaf(wA, xA.x, z0); z1 = fmaf(wA, xA.y, z1);
        z0 = fmaf(wB, xB_.x, z0); z1 = fmaf(wB, xB_.y, z1);
        z0 = fmaf(wC, xC.x, z0); z1 = fmaf(wC, xC.y, z1);
        z0 = fmaf(wD, xD.x, z0); z1 = fmaf(wD, xD.y, z1);
      }
      wsum += wA + wB + wC + wD;
    }
    for (; k < (int)n; ++k) {               // tail
      unsigned sA = __shfl(msrc, k); float wA = __shfl(mw, k);
      if (XB) {
        unsigned hA = *(const unsigned*)&xb[((size_t)sA << 7) + (l << 1)];
        z0 = fmaf(wA, bf2f((unsigned short)(hA & 0xFFFFu)), z0);
        z1 = fmaf(wA, bf2f((unsigned short)(hA >> 16)), z1);
      } else {
        float2 xA = *(const float2*)&x[((size_t)sA << 7) + (l << 1)];
        z0 = fmaf(wA, xA.x, z0); z1 = fmaf(wA, xA.y, z1);
      }
      wsum += wA;
    }
  }
  *(float2*)&z[((size_t)v << 7) + (l << 1)] = make_float2(z0, z1);
  if (l == 0) sumw_out[v] = f2bf(wsum);   // separate array: no race with s reads
}

// ---- out = relu(z @ W^T + sumw*b), f32 in place; W in LDS as bf16 (32KB) ---
__global__ __launch_bounds__(THREADS) void k_out(
    const float* __restrict__ W, const float* __restrict__ c0,
    const float* __restrict__ c1, const int* __restrict__ hdr,
    const unsigned short* __restrict__ sumw, float* __restrict__ zo) {
  const float* bias = hdr[1] ? c0 : c1;
  __shared__ unsigned short wsT[128 * 128];  // W transposed, bf16
  const int t = threadIdx.x;
  #pragma unroll
  for (int i = 0; i < 4; ++i) {
    int idx = i * THREADS + t;
    int o = (idx & 31) * 4;
    int k = (idx >> 5) * 4;
    float4 r0 = *(const float4*)&W[(o + 0) * 128 + k];
    float4 r1 = *(const float4*)&W[(o + 1) * 128 + k];
    float4 r2 = *(const float4*)&W[(o + 2) * 128 + k];
    float4 r3 = *(const float4*)&W[(o + 3) * 128 + k];
    *(ushort4*)&wsT[(k + 0) * 128 + o] = make_ushort4(f2bf(r0.x), f2bf(r1.x), f2bf(r2.x), f2bf(r3.x));
    *(ushort4*)&wsT[(k + 1) * 128 + o] = make_ushort4(f2bf(r0.y), f2bf(r1.y), f2bf(r2.y), f2bf(r3.y));
    *(ushort4*)&wsT[(k + 2) * 128 + o] = make_ushort4(f2bf(r0.z), f2bf(r1.z), f2bf(r2.z), f2bf(r3.z));
    *(ushort4*)&wsT[(k + 3) * 128 + o] = make_ushort4(f2bf(r0.w), f2bf(r1.w), f2bf(r2.w), f2bf(r3.w));
  }
  __syncthreads();

  const int tcol = t & 15;
  const int trow = t >> 4;
  const int row0 = blockIdx.x * 64 + trow * 4;
  int rc[4];
  #pragma unroll
  for (int r = 0; r < 4; ++r) { int rr = row0 + r; rc[r] = rr < NN ? rr : (NN - 1); }

  float acc[4][8];
  #pragma unroll
  for (int r = 0; r < 4; ++r)
    #pragma unroll
    for (int c = 0; c < 8; ++c) acc[r][c] = 0.f;

  for (int k0 = 0; k0 < 128; k0 += 4) {
    float a_[4][4];
    #pragma unroll
    for (int r = 0; r < 4; ++r)
      *(float4*)a_[r] = *(const float4*)&zo[((size_t)rc[r] << 7) + k0];
    #pragma unroll
    for (int kk = 0; kk < 4; ++kk) {
      int k = k0 + kk;
      ushort4 w0u = *(const ushort4*)&wsT[k * 128 + 4 * tcol];
      ushort4 w1u = *(const ushort4*)&wsT[k * 128 + 64 + 4 * tcol];
      #pragma unroll
      for (int r = 0; r < 4; ++r) {
        float av = a_[r][kk];
        acc[r][0] = fmaf(av, bf2f(w0u.x), acc[r][0]);
        acc[r][1] = fmaf(av, bf2f(w0u.y), acc[r][1]);
        acc[r][2] = fmaf(av, bf2f(w0u.z), acc[r][2]);
        acc[r][3] = fmaf(av, bf2f(w0u.w), acc[r][3]);
        acc[r][4] = fmaf(av, bf2f(w1u.x), acc[r][4]);
        acc[r][5] = fmaf(av, bf2f(w1u.y), acc[r][5]);
        acc[r][6] = fmaf(av, bf2f(w1u.z), acc[r][6]);
        acc[r][7] = fmaf(av, bf2f(w1u.w), acc[r][7]);
      }
    }
  }
  __syncthreads();   // all reads of this block's rows done before in-place writes

  float4 b0 = *(const float4*)&bias[4 * tcol];
  float4 b1 = *(const float4*)&bias[64 + 4 * tcol];
  #pragma unroll
  for (int r = 0; r < 4; ++r) {
    int rowg = row0 + r;
    if (rowg >= NN) continue;
    float sw = bf2f(sumw[rowg]);
    float4 o0, o1;
    o0.x = fmaxf(acc[r][0] + sw * b0.x, 0.f);
    o0.y = fmaxf(acc[r][1] + sw * b0.y, 0.f);
    o0.z = fmaxf(acc[r][2] + sw * b0.z, 0.f);
    o0.w = fmaxf(acc[r][3] + sw * b0.w, 0.f);
    o1.x = fmaxf(acc[r][4] + sw * b1.x, 0.f);
    o1.y = fmaxf(acc[r][5] + sw * b1.y, 0.f);
    o1.z = fmaxf(acc[r][6] + sw * b1.z, 0.f);
    o1.w = fmaxf(acc[r][7] + sw * b1.w, 0.f);
    *(float4*)&zo[((size_t)rowg << 7) + 4 * tcol] = o0;
    *(float4*)&zo[((size_t)rowg << 7) + 64 + 4 * tcol] = o1;
  }
}

// ---- edge_index -> f32 at f32 els [12.8M,16M); stomps tier-C scratch -------
__global__ void k_copy_ei_sd(const void* __restrict__ ei, float* __restrict__ out1) {
  __shared__ int smode;
  if (threadIdx.x == 0) {
    int odd_nz = 0, even_big = 0;
    const unsigned* u = (const unsigned*)ei;
    for (int i = 0; i < 128; ++i) {
      unsigned ww = u[i];
      if (i & 1) odd_nz += (ww != 0u);
      else       even_big += (ww >= 1000000u);
    }
    smode = (odd_nz == 0) ? 1 : ((even_big > 32) ? 2 : 0);
  }
  __syncthreads();
  int mode = smode;
  int i2 = (blockIdx.x * THREADS + threadIdx.x) * 2;
  if (i2 >= 2 * EE) return;
  int v0, v1;
  if (mode == 1)      { v0 = ((const int*)ei)[2 * (size_t)i2]; v1 = ((const int*)ei)[2 * (size_t)i2 + 2]; }
  else if (mode == 2) { v0 = (int)((const float*)ei)[i2]; v1 = (int)((const float*)ei)[i2 + 1]; }
  else                { v0 = ((const int*)ei)[i2]; v1 = ((const int*)ei)[i2 + 1]; }
  *(float2*)&out1[i2] = make_float2((float)v0, (float)v1);
}

extern "C" void kernel_launch(void* const* d_in, const int* in_sizes, int n_in,
                              void* d_out, int out_size, void* d_ws, size_t ws_size,
                              hipStream_t stream) {
  // ---- identify inputs by SIZE, fallback positional ----
  const void *px = nullptr, *pei = nullptr, *pW = nullptr, *pc0 = nullptr, *pc1 = nullptr;
  for (int i = 0; i < n_in; ++i) {
    long long sz = in_sizes[i];
    if (sz == (long long)NN * 128 * 4) px = d_in[i];
    else if (sz == (long long)NN * 128 && !px) px = d_in[i];
    else if (sz == 2LL * EE || sz == 4LL * EE || sz == 16LL * EE) pei = d_in[i];
    else if (sz == 128 * 128 || sz == 128 * 128 * 4) pW = d_in[i];
    else if (sz == 128 || sz == 512) { if (!pc0) pc0 = d_in[i]; else if (!pc1) pc1 = d_in[i]; }
  }
  if (!px)  px  = d_in[0];
  if (!pei) pei = d_in[1];
  if (!pW)  pW  = d_in[2];
  if (!pc0) pc0 = d_in[3];
  if (!pc1) pc1 = d_in[4];

  // ---- tier selection + layout ----
  int st, usexb;
  char* sb;
  if (ws_size >= (size_t)46000000)      { sb = (char*)d_ws; st = 16; usexb = 1; }
  else if (ws_size >= (size_t)34000000) { sb = (char*)d_ws; st = 1;  usexb = 1; }
  else { sb = (char*)d_out + 51200000u; st = 1; usexb = 0; }

  size_t off = 0;
  auto take = [&](size_t b) { char* r = sb + off; off = (off + b + 255) & ~(size_t)255; return r; };
  unsigned*       ent_src = (unsigned*)take((size_t)EE * 4);
  unsigned*       degcur  = (unsigned*)take((size_t)NN * st * 4);
  float*          denom   = (float*)take((size_t)NN * st * 4);
  unsigned short* sbuf    = (unsigned short*)take((size_t)NN * 2);
  unsigned short* sumw    = (unsigned short*)take((size_t)NN * 2);
  unsigned*       part    = (unsigned*)take(2048);
  int*            hdr     = (int*)take(64);
  float*          gc      = (float*)take(129 * 4);
  unsigned short* xb      = usexb ? (unsigned short*)take((size_t)NN * 128 * 2) : nullptr;

  float* out0 = (float*)d_out;                 // [NN,128] f32
  float* out1 = (float*)d_out + EI_F32;        // [2,EE] f32

  const int nb_n  = (NN + THREADS - 1) / THREADS;   // 391
  const int nb_n4 = (NN + 3) / 4;                   // 25000
  const int nb_e  = (ETT + THREADS - 1) / THREADS;  // 6641
  const int nb_e2 = (EE + THREADS - 1) / THREADS;   // 6250

  k_setup<<<nb_n, THREADS, 0, stream>>>((const unsigned*)pei, (const float*)pc0,
                                        (const float*)pc1, (const float*)pW,
                                        hdr, gc, degcur, denom, st);
  k_sq<<<nb_n4, THREADS, 0, stream>>>((const float*)px, gc, sbuf, xb, usexb);
  k_edge1<<<nb_e, THREADS, 0, stream>>>(pei, hdr, sbuf, degcur, denom, st);
  k_part<<<nb_n, THREADS, 0, stream>>>(degcur, part, st);
  k_scan_top<<<1, 512, 0, stream>>>(part, nb_n);
  k_scan_final<<<nb_n, THREADS, 0, stream>>>(degcur, part, st);
  k_edge2<<<nb_e2, THREADS, 0, stream>>>(pei, hdr, degcur, ent_src, st);
  if (usexb)
    k_agg<1><<<nb_n4, THREADS, 0, stream>>>(degcur, ent_src, denom, sbuf, sumw,
                                            (const float*)px, xb, out0, st);
  else
    k_agg<0><<<nb_n4, THREADS, 0, stream>>>(degcur, ent_src, denom, sbuf, sumw,
                                            (const float*)px, nullptr, out0, st);
  k_out<<<(NN + 63) / 64, THREADS, 0, stream>>>((const float*)pW, (const float*)pc0,
                                                (const float*)pc1, hdr, sumw, out0);
  k_copy_ei_sd<<<nb_e2, THREADS, 0, stream>>>(pei, out1);
}

// Round 14
// 462.429 us; speedup vs baseline: 1.0530x; 1.0530x over previous
//
#include <hip/hip_runtime.h>
#include <hip/hip_bf16.h>

#define THREADS 256
#define NN 100000
#define EE 1600000
#define ETT (EE + NN)

// ===== VERIFIED OUTPUT MODEL: d_out is FLOAT32, 16M f32 els =====
//   out : f32 els [0, 12.8M)    ei : f32 els [12.8M, 16M)
#define EI_F32  12800000u
// Scratch tiers:
//   A: ws>=41MB : d_ws, NC=8 XCD-local atomic copies, bf16-x copy   (~39.5MB)
//   B: ws>=34MB : d_ws, NC=1, bf16-x copy                            (~33.8MB)
//   C: else     : d_out ei-region (12.8MB), NC=1, no x copy          (~8.1MB)

__device__ __forceinline__ unsigned short f2bf(float f) {
  unsigned u = __float_as_uint(f);
  u = u + 0x7FFFu + ((u >> 16) & 1u);   // RNE
  return (unsigned short)(u >> 16);
}
__device__ __forceinline__ float bf2f(unsigned short v) {
  return __uint_as_float((unsigned)v << 16);
}
__device__ __forceinline__ float lrelu(float a) { return a > 0.f ? a : 0.2f * a; }

// edge_index element fetch: mode 0=int32, 1=int64(low word), 2=fp32
__device__ __forceinline__ int load_edge(const void* ei, int mode, int idx) {
  int v;
  if (mode == 1)      v = ((const int*)ei)[2 * (size_t)idx];
  else if (mode == 2) v = (int)(((const float*)ei)[idx]);
  else                v = ((const int*)ei)[idx];
  return ((unsigned)v < NN) ? v : 0;
}

// ---- setup: zero deg/den copies; block 0: detect + g/c precompute ----------
__global__ void k_setup(const unsigned* __restrict__ ei_u,
                        const float* __restrict__ c0, const float* __restrict__ c1,
                        const float* __restrict__ W,
                        int* __restrict__ hdr, float* __restrict__ gc,
                        unsigned* __restrict__ deg8, float* __restrict__ den8,
                        int NC) {
  int i = blockIdx.x * THREADS + threadIdx.x;
  if (i < NN) {
    for (int x = 0; x < NC; ++x) {
      deg8[(size_t)x * NN + i] = 0u;
      den8[(size_t)x * NN + i] = 0.f;
    }
  }
  if (blockIdx.x != 0) return;
  __shared__ int sbias;
  int t = threadIdx.x;
  if (t < 64) {
    int odd_nz = 0, even_big = 0;
    for (int k = t; k < 2048; k += 64) {
      unsigned w = ei_u[k];
      if (k & 1) odd_nz += (w != 0u);
      else       even_big += (w >= 1000000u);
    }
    #pragma unroll
    for (int m = 1; m < 64; m <<= 1) {
      odd_nz += __shfl_xor(odd_nz, m, 64);
      even_big += __shfl_xor(even_big, m, 64);
    }
    const unsigned* u0 = (const unsigned*)c0;
    const unsigned* u1 = (const unsigned*)c1;
    unsigned s0 = u0[t] | u0[t + 64], s1 = u1[t] | u1[t + 64];
    #pragma unroll
    for (int m = 1; m < 64; m <<= 1) {
      s0 |= __shfl_xor(s0, m, 64);
      s1 |= __shfl_xor(s1, m, 64);
    }
    if (t == 0) {
      hdr[0] = (odd_nz == 0) ? 1 : ((even_big > 512) ? 2 : 0);
      int b = (s0 == 0u) ? 1 : ((s1 == 0u) ? 0 : 1);
      hdr[1] = b;
      sbias = b;
    }
  }
  __syncthreads();
  const float* bias = sbias ? c0 : c1;
  const float* att  = sbias ? c1 : c0;
  if (t < 128) {
    float g = 0.f;
    for (int o = 0; o < 128; ++o) g = fmaf(att[o], W[o * 128 + t], g);
    gc[t] = g;
    if (t == 0) {
      float c = 0.f;
      for (int o = 0; o < 128; ++o) c = fmaf(att[o], bias[o], c);
      gc[128] = c;
    }
  }
}

// ---- s[i] = bf16(x[i].g + c); optional bf16 copy of x ----------------------
__global__ __launch_bounds__(THREADS) void k_sq(const float* __restrict__ x,
                                                const float* __restrict__ gc,
                                                unsigned short* __restrict__ s,
                                                unsigned short* __restrict__ xb,
                                                int wantxb) {
  int node = blockIdx.x * 4 + (threadIdx.x >> 6);
  if (node >= NN) return;
  int l = threadIdx.x & 63;
  float2 xv = *(const float2*)&x[(size_t)node * 128 + l * 2];
  if (wantxb) {
    unsigned pk = (unsigned)f2bf(xv.x) | ((unsigned)f2bf(xv.y) << 16);
    *(unsigned*)&xb[(size_t)node * 128 + l * 2] = pk;
  }
  float2 gv = *(const float2*)&gc[l * 2];
  float v = xv.x * gv.x + xv.y * gv.y;
  #pragma unroll
  for (int m = 1; m < 64; m <<= 1) v += __shfl_xor(v, m, 64);
  if (l == 0) s[node] = f2bf(v + gc[128]);
}

// ---- edge pass 1: den8[c] += exp(alpha) (by src); deg8[c]++ (by dst) -------
// c = blockIdx % NC: same-copy atomics stay XCD-local (L2-resident lines).
__global__ void k_edge1(const void* __restrict__ ei, const int* __restrict__ hdr,
                        const unsigned short* __restrict__ s,
                        unsigned* __restrict__ deg8, float* __restrict__ den8,
                        int NC) {
  int e = blockIdx.x * THREADS + threadIdx.x;
  if (e >= ETT) return;
  size_t cofs = (size_t)(blockIdx.x % NC) * NN;
  int mode = hdr[0];
  if (e < EE) {
    int src = load_edge(ei, mode, e);
    int dst = load_edge(ei, mode, EE + e);
    float a = lrelu(bf2f(s[dst]) + bf2f(s[src]));
    atomicAdd(&den8[cofs + src], __expf(fminf(a, 60.f)));
    atomicAdd(&deg8[cofs + dst], 1u);
  } else {
    int i = e - EE;
    float a = lrelu(2.f * bf2f(s[i]));
    atomicAdd(&den8[cofs + i], __expf(fminf(a, 60.f)));
  }
}

// ---- prefix scan over summed copies ----------------------------------------
__global__ void k_part(const unsigned* __restrict__ deg8, unsigned* __restrict__ part,
                       int NC) {
  int i = blockIdx.x * THREADS + threadIdx.x;
  unsigned v = 0u;
  if (i < NN)
    for (int x = 0; x < NC; ++x) v += deg8[(size_t)x * NN + i];
  #pragma unroll
  for (int m = 1; m < 64; m <<= 1) v += __shfl_xor(v, m, 64);
  __shared__ unsigned sm[4];
  if ((threadIdx.x & 63) == 0) sm[threadIdx.x >> 6] = v;
  __syncthreads();
  if (threadIdx.x == 0) part[blockIdx.x] = sm[0] + sm[1] + sm[2] + sm[3];
}

__global__ void k_scan_top(unsigned* __restrict__ part, int nb) {  // 1 block, 512 thr
  int t = threadIdx.x;
  int lane = t & 63, w = t >> 6;
  unsigned v = (t < nb) ? part[t] : 0u;
  unsigned inc = v;
  #pragma unroll
  for (int d = 1; d < 64; d <<= 1) {
    unsigned o = __shfl_up(inc, d, 64);
    if (lane >= d) inc += o;
  }
  __shared__ unsigned wsum[8];
  if (lane == 63) wsum[w] = inc;
  __syncthreads();
  unsigned off = 0;
  for (int j = 0; j < w; ++j) off += wsum[j];
  if (t < nb) part[t] = inc - v + off;  // exclusive
}

// rowptr[i]=excl; per-copy bases into deg8 (in place); denomc[i]=sum(den8) ---
__global__ void k_scan_final(unsigned* __restrict__ deg8, const float* __restrict__ den8,
                             const unsigned* __restrict__ part,
                             unsigned* __restrict__ rowptr, float* __restrict__ denomc,
                             int NC) {
  int i = blockIdx.x * THREADS + threadIdx.x;
  int lane = threadIdx.x & 63, w = threadIdx.x >> 6;
  unsigned d[8];
  unsigned tot = 0u;
  if (i < NN)
    for (int x = 0; x < NC; ++x) { d[x] = deg8[(size_t)x * NN + i]; tot += d[x]; }
  unsigned inc = tot;
  #pragma unroll
  for (int m = 1; m < 64; m <<= 1) {
    unsigned o = __shfl_up(inc, m, 64);
    if (lane >= m) inc += o;
  }
  __shared__ unsigned wsum[4];
  if (lane == 63) wsum[w] = inc;
  __syncthreads();
  unsigned off = part[blockIdx.x];
  for (int j = 0; j < w; ++j) off += wsum[j];
  if (i < NN) {
    unsigned excl = inc - tot + off;
    rowptr[i] = excl;
    unsigned run = excl;
    for (int x = 0; x < NC; ++x) { deg8[(size_t)x * NN + i] = run; run += d[x]; }
    float ds = 0.f;
    for (int x = 0; x < NC; ++x) ds += den8[(size_t)x * NN + i];
    denomc[i] = ds;
    if (i == 0) rowptr[NN] = (unsigned)EE;
  }
}

// ---- edge pass 2: CSR fill via XCD-local cursor (deg8 now holds bases) -----
__global__ void k_edge2(const void* __restrict__ ei, const int* __restrict__ hdr,
                        unsigned* __restrict__ deg8, unsigned* __restrict__ ent_src,
                        int NC) {
  int e = blockIdx.x * THREADS + threadIdx.x;
  if (e >= EE) return;
  size_t cofs = (size_t)(blockIdx.x % NC) * NN;   // SAME mapping as k_edge1
  int mode = hdr[0];
  int src = load_edge(ei, mode, e);
  int dst = load_edge(ei, mode, EE + e);
  unsigned pos = atomicAdd(&deg8[cofs + dst], 1u);
  if (pos < (unsigned)EE) ent_src[pos] = (unsigned)src;
}

// ---- aggregation: stage (src, w) lane-parallel; unroll-4 row gathers -------
template<int XB>
__global__ __launch_bounds__(THREADS) void k_agg(
    const unsigned* __restrict__ rowptr, const unsigned* __restrict__ ent_src,
    const float* __restrict__ denom, const unsigned short* __restrict__ s,
    unsigned short* __restrict__ sumw_out,
    const float* __restrict__ x, const unsigned short* __restrict__ xb,
    float* __restrict__ z) {
  int v = blockIdx.x * 4 + (threadIdx.x >> 6);
  if (v >= NN) return;
  int l = threadIdx.x & 63;
  unsigned beg = rowptr[v], end = rowptr[v + 1];
  float sv = bf2f(s[v]);
  float wself = __expf(fminf(lrelu(2.f * sv), 60.f)) / denom[v];
  float z0, z1, wsum = wself;
  if (XB) {
    unsigned hv = *(const unsigned*)&xb[((size_t)v << 7) + (l << 1)];
    z0 = wself * bf2f((unsigned short)(hv & 0xFFFFu));
    z1 = wself * bf2f((unsigned short)(hv >> 16));
  } else {
    float2 xv = *(const float2*)&x[((size_t)v << 7) + (l << 1)];
    z0 = wself * xv.x; z1 = wself * xv.y;
  }

  for (unsigned j0 = beg; j0 < end; j0 += 64) {
    unsigned n = end - j0; if (n > 64u) n = 64u;
    unsigned msrc = 0u; float mw = 0.f;
    if (l < (int)n) {                       // lane-parallel stage: src + w
      msrc = ent_src[j0 + l];
      float a = lrelu(sv + bf2f(s[msrc]));
      mw = __expf(fminf(a, 60.f)) / denom[msrc];
    }
    int k = 0;
    for (; k + 4 <= (int)n; k += 4) {       // 4 independent gathers in flight
      unsigned sA = __shfl(msrc, k);     float wA = __shfl(mw, k);
      unsigned sB = __shfl(msrc, k + 1); float wB = __shfl(mw, k + 1);
      unsigned sC = __shfl(msrc, k + 2); float wC = __shfl(mw, k + 2);
      unsigned sD = __shfl(msrc, k + 3); float wD = __shfl(mw, k + 3);
      if (XB) {
        unsigned hA = *(const unsigned*)&xb[((size_t)sA << 7) + (l << 1)];
        unsigned hB = *(const unsigned*)&xb[((size_t)sB << 7) + (l << 1)];
        unsigned hC = *(const unsigned*)&xb[((size_t)sC << 7) + (l << 1)];
        unsigned hD = *(const unsigned*)&xb[((size_t)sD << 7) + (l << 1)];
        z0 = fmaf(wA, bf2f((unsigned short)(hA & 0xFFFFu)), z0);
        z1 = fmaf(wA, bf2f((unsigned short)(hA >> 16)), z1);
        z0 = fmaf(wB, bf2f((unsigned short)(hB & 0xFFFFu)), z0);
        z1 = fmaf(wB, bf2f((unsigned short)(hB >> 16)), z1);
        z0 = fmaf(wC, bf2f((unsigned short)(hC & 0xFFFFu)), z0);
        z1 = fmaf(wC, bf2f((unsigned short)(hC >> 16)), z1);
        z0 = fmaf(wD, bf2f((unsigned short)(hD & 0xFFFFu)), z0);
        z1 = fmaf(wD, bf2f((unsigned short)(hD >> 16)), z1);
      } else {
        float2 xA = *(const float2*)&x[((size_t)sA << 7) + (l << 1)];
        float2 xB_ = *(const float2*)&x[((size_t)sB << 7) + (l << 1)];
        float2 xC = *(const float2*)&x[((size_t)sC << 7) + (l << 1)];
        float2 xD = *(const float2*)&x[((size_t)sD << 7) + (l << 1)];
        z0 = fmaf(wA, xA.x, z0); z1 = fmaf(wA, xA.y, z1);
        z0 = fmaf(wB, xB_.x, z0); z1 = fmaf(wB, xB_.y, z1);
        z0 = fmaf(wC, xC.x, z0); z1 = fmaf(wC, xC.y, z1);
        z0 = fmaf(wD, xD.x, z0); z1 = fmaf(wD, xD.y, z1);
      }
      wsum += wA + wB + wC + wD;
    }
    for (; k < (int)n; ++k) {               // tail
      unsigned sA = __shfl(msrc, k); float wA = __shfl(mw, k);
      if (XB) {
        unsigned hA = *(const unsigned*)&xb[((size_t)sA << 7) + (l << 1)];
        z0 = fmaf(wA, bf2f((unsigned short)(hA & 0xFFFFu)), z0);
        z1 = fmaf(wA, bf2f((unsigned short)(hA >> 16)), z1);
      } else {
        float2 xA = *(const float2*)&x[((size_t)sA << 7) + (l << 1)];
        z0 = fmaf(wA, xA.x, z0); z1 = fmaf(wA, xA.y, z1);
      }
      wsum += wA;
    }
  }
  *(float2*)&z[((size_t)v << 7) + (l << 1)] = make_float2(z0, z1);
  if (l == 0) sumw_out[v] = f2bf(wsum);
}

// ---- out = relu(z @ W^T + sumw*b), f32 in place; W in LDS as bf16 (32KB) ---
__global__ __launch_bounds__(THREADS) void k_out(
    const float* __restrict__ W, const float* __restrict__ c0,
    const float* __restrict__ c1, const int* __restrict__ hdr,
    const unsigned short* __restrict__ sumw, float* __restrict__ zo) {
  const float* bias = hdr[1] ? c0 : c1;
  __shared__ unsigned short wsT[128 * 128];  // W transposed, bf16
  const int t = threadIdx.x;
  #pragma unroll
  for (int i = 0; i < 4; ++i) {
    int idx = i * THREADS + t;
    int o = (idx & 31) * 4;
    int k = (idx >> 5) * 4;
    float4 r0 = *(const float4*)&W[(o + 0) * 128 + k];
    float4 r1 = *(const float4*)&W[(o + 1) * 128 + k];
    float4 r2 = *(const float4*)&W[(o + 2) * 128 + k];
    float4 r3 = *(const float4*)&W[(o + 3) * 128 + k];
    *(ushort4*)&wsT[(k + 0) * 128 + o] = make_ushort4(f2bf(r0.x), f2bf(r1.x), f2bf(r2.x), f2bf(r3.x));
    *(ushort4*)&wsT[(k + 1) * 128 + o] = make_ushort4(f2bf(r0.y), f2bf(r1.y), f2bf(r2.y), f2bf(r3.y));
    *(ushort4*)&wsT[(k + 2) * 128 + o] = make_ushort4(f2bf(r0.z), f2bf(r1.z), f2bf(r2.z), f2bf(r3.z));
    *(ushort4*)&wsT[(k + 3) * 128 + o] = make_ushort4(f2bf(r0.w), f2bf(r1.w), f2bf(r2.w), f2bf(r3.w));
  }
  __syncthreads();

  const int tcol = t & 15;
  const int trow = t >> 4;
  const int row0 = blockIdx.x * 64 + trow * 4;
  int rc[4];
  #pragma unroll
  for (int r = 0; r < 4; ++r) { int rr = row0 + r; rc[r] = rr < NN ? rr : (NN - 1); }

  float acc[4][8];
  #pragma unroll
  for (int r = 0; r < 4; ++r)
    #pragma unroll
    for (int c = 0; c < 8; ++c) acc[r][c] = 0.f;

  for (int k0 = 0; k0 < 128; k0 += 4) {
    float a_[4][4];
    #pragma unroll
    for (int r = 0; r < 4; ++r)
      *(float4*)a_[r] = *(const float4*)&zo[((size_t)rc[r] << 7) + k0];
    #pragma unroll
    for (int kk = 0; kk < 4; ++kk) {
      int k = k0 + kk;
      ushort4 w0u = *(const ushort4*)&wsT[k * 128 + 4 * tcol];
      ushort4 w1u = *(const ushort4*)&wsT[k * 128 + 64 + 4 * tcol];
      #pragma unroll
      for (int r = 0; r < 4; ++r) {
        float av = a_[r][kk];
        acc[r][0] = fmaf(av, bf2f(w0u.x), acc[r][0]);
        acc[r][1] = fmaf(av, bf2f(w0u.y), acc[r][1]);
        acc[r][2] = fmaf(av, bf2f(w0u.z), acc[r][2]);
        acc[r][3] = fmaf(av, bf2f(w0u.w), acc[r][3]);
        acc[r][4] = fmaf(av, bf2f(w1u.x), acc[r][4]);
        acc[r][5] = fmaf(av, bf2f(w1u.y), acc[r][5]);
        acc[r][6] = fmaf(av, bf2f(w1u.z), acc[r][6]);
        acc[r][7] = fmaf(av, bf2f(w1u.w), acc[r][7]);
      }
    }
  }
  __syncthreads();   // all reads of this block's rows done before in-place writes

  float4 b0 = *(const float4*)&bias[4 * tcol];
  float4 b1 = *(const float4*)&bias[64 + 4 * tcol];
  #pragma unroll
  for (int r = 0; r < 4; ++r) {
    int rowg = row0 + r;
    if (rowg >= NN) continue;
    float sw = bf2f(sumw[rowg]);
    float4 o0, o1;
    o0.x = fmaxf(acc[r][0] + sw * b0.x, 0.f);
    o0.y = fmaxf(acc[r][1] + sw * b0.y, 0.f);
    o0.z = fmaxf(acc[r][2] + sw * b0.z, 0.f);
    o0.w = fmaxf(acc[r][3] + sw * b0.w, 0.f);
    o1.x = fmaxf(acc[r][4] + sw * b1.x, 0.f);
    o1.y = fmaxf(acc[r][5] + sw * b1.y, 0.f);
    o1.z = fmaxf(acc[r][6] + sw * b1.z, 0.f);
    o1.w = fmaxf(acc[r][7] + sw * b1.w, 0.f);
    *(float4*)&zo[((size_t)rowg << 7) + 4 * tcol] = o0;
    *(float4*)&zo[((size_t)rowg << 7) + 64 + 4 * tcol] = o1;
  }
}

// ---- edge_index -> f32 at f32 els [12.8M,16M); stomps tier-C scratch -------
__global__ void k_copy_ei_sd(const void* __restrict__ ei, float* __restrict__ out1) {
  __shared__ int smode;
  if (threadIdx.x == 0) {
    int odd_nz = 0, even_big = 0;
    const unsigned* u = (const unsigned*)ei;
    for (int i = 0; i < 128; ++i) {
      unsigned ww = u[i];
      if (i & 1) odd_nz += (ww != 0u);
      else       even_big += (ww >= 1000000u);
    }
    smode = (odd_nz == 0) ? 1 : ((even_big > 32) ? 2 : 0);
  }
  __syncthreads();
  int mode = smode;
  int i2 = (blockIdx.x * THREADS + threadIdx.x) * 2;
  if (i2 >= 2 * EE) return;
  int v0, v1;
  if (mode == 1)      { v0 = ((const int*)ei)[2 * (size_t)i2]; v1 = ((const int*)ei)[2 * (size_t)i2 + 2]; }
  else if (mode == 2) { v0 = (int)((const float*)ei)[i2]; v1 = (int)((const float*)ei)[i2 + 1]; }
  else                { v0 = ((const int*)ei)[i2]; v1 = ((const int*)ei)[i2 + 1]; }
  *(float2*)&out1[i2] = make_float2((float)v0, (float)v1);
}

extern "C" void kernel_launch(void* const* d_in, const int* in_sizes, int n_in,
                              void* d_out, int out_size, void* d_ws, size_t ws_size,
                              hipStream_t stream) {
  // ---- identify inputs by SIZE, fallback positional ----
  const void *px = nullptr, *pei = nullptr, *pW = nullptr, *pc0 = nullptr, *pc1 = nullptr;
  for (int i = 0; i < n_in; ++i) {
    long long sz = in_sizes[i];
    if (sz == (long long)NN * 128 * 4) px = d_in[i];
    else if (sz == (long long)NN * 128 && !px) px = d_in[i];
    else if (sz == 2LL * EE || sz == 4LL * EE || sz == 16LL * EE) pei = d_in[i];
    else if (sz == 128 * 128 || sz == 128 * 128 * 4) pW = d_in[i];
    else if (sz == 128 || sz == 512) { if (!pc0) pc0 = d_in[i]; else if (!pc1) pc1 = d_in[i]; }
  }
  if (!px)  px  = d_in[0];
  if (!pei) pei = d_in[1];
  if (!pW)  pW  = d_in[2];
  if (!pc0) pc0 = d_in[3];
  if (!pc1) pc1 = d_in[4];

  // ---- tier selection ----
  int NC, usexb;
  char* sb;
  if (ws_size >= (size_t)41000000)      { sb = (char*)d_ws; NC = 8; usexb = 1; }
  else if (ws_size >= (size_t)34000000) { sb = (char*)d_ws; NC = 1; usexb = 1; }
  else { sb = (char*)d_out + 51200000u; NC = 1; usexb = 0; }

  size_t off = 0;
  auto take = [&](size_t b) { char* r = sb + off; off = (off + b + 255) & ~(size_t)255; return r; };
  unsigned*       ent_src = (unsigned*)take((size_t)EE * 4);
  unsigned*       deg8    = (unsigned*)take((size_t)NN * NC * 4);
  float*          den8    = (float*)take((size_t)NN * NC * 4);
  unsigned*       rowptr  = (unsigned*)take((size_t)(NN + 1) * 4);
  float*          denomc  = (float*)take((size_t)NN * 4);
  unsigned short* sbuf    = (unsigned short*)take((size_t)NN * 2);
  unsigned short* sumw    = (unsigned short*)take((size_t)NN * 2);
  unsigned*       part    = (unsigned*)take(2048);
  int*            hdr     = (int*)take(64);
  float*          gc      = (float*)take(129 * 4);
  unsigned short* xb      = usexb ? (unsigned short*)take((size_t)NN * 128 * 2) : nullptr;

  float* out0 = (float*)d_out;                 // [NN,128] f32
  float* out1 = (float*)d_out + EI_F32;        // [2,EE] f32

  const int nb_n  = (NN + THREADS - 1) / THREADS;   // 391
  const int nb_n4 = (NN + 3) / 4;                   // 25000
  const int nb_e  = (ETT + THREADS - 1) / THREADS;  // 6641
  const int nb_e2 = (EE + THREADS - 1) / THREADS;   // 6250

  k_setup<<<nb_n, THREADS, 0, stream>>>((const unsigned*)pei, (const float*)pc0,
                                        (const float*)pc1, (const float*)pW,
                                        hdr, gc, deg8, den8, NC);
  k_sq<<<nb_n4, THREADS, 0, stream>>>((const float*)px, gc, sbuf, xb, usexb);
  k_edge1<<<nb_e, THREADS, 0, stream>>>(pei, hdr, sbuf, deg8, den8, NC);
  k_part<<<nb_n, THREADS, 0, stream>>>(deg8, part, NC);
  k_scan_top<<<1, 512, 0, stream>>>(part, nb_n);
  k_scan_final<<<nb_n, THREADS, 0, stream>>>(deg8, den8, part, rowptr, denomc, NC);
  k_edge2<<<nb_e2, THREADS, 0, stream>>>(pei, hdr, deg8, ent_src, NC);
  if (usexb)
    k_agg<1><<<nb_n4, THREADS, 0, stream>>>(rowptr, ent_src, denomc, sbuf, sumw,
                                            (const float*)px, xb, out0);
  else
    k_agg<0><<<nb_n4, THREADS, 0, stream>>>(rowptr, ent_src, denomc, sbuf, sumw,
                                            (const float*)px, nullptr, out0);
  k_out<<<(NN + 63) / 64, THREADS, 0, stream>>>((const float*)pW, (const float*)pc0,
                                                (const float*)pc1, hdr, sumw, out0);
  k_copy_ei_sd<<<nb_e2, THREADS, 0, stream>>>(pei, out1);
}

// Round 15
// 360.566 us; speedup vs baseline: 1.3505x; 1.2825x over previous
//
#include <hip/hip_runtime.h>
#include <hip/hip_bf16.h>

#define THREADS 256
#define NN 100000
#define EE 1600000
#define ETT (EE + NN)

// ===== VERIFIED OUTPUT MODEL: d_out is FLOAT32, 16M f32 els =====
//   out : f32 els [0, 12.8M)    ei : f32 els [12.8M, 16M)
#define EI_F32  12800000u
// Scratch tiers:
//   A: ws>=38MB : d_ws, bf16-x copy                 (~37MB)
//   C: else     : d_out ei-region (12.8MB), no x copy (~11.3MB; stomped by copy_ei)

__device__ __forceinline__ unsigned short f2bf(float f) {
  unsigned u = __float_as_uint(f);
  u = u + 0x7FFFu + ((u >> 16) & 1u);   // RNE
  return (unsigned short)(u >> 16);
}
__device__ __forceinline__ float bf2f(unsigned short v) {
  return __uint_as_float((unsigned)v << 16);
}
__device__ __forceinline__ float lrelu(float a) { return a > 0.f ? a : 0.2f * a; }

// edge_index element fetch: mode 0=int32, 1=int64(low word), 2=fp32
__device__ __forceinline__ int load_edge(const void* ei, int mode, int idx) {
  int v;
  if (mode == 1)      v = ((const int*)ei)[2 * (size_t)idx];
  else if (mode == 2) v = (int)(((const float*)ei)[idx]);
  else                v = ((const int*)ei)[idx];
  return ((unsigned)v < NN) ? v : 0;
}

// ---- setup: zero deg/den; block 0: detect + g/c precompute -----------------
__global__ void k_setup(const unsigned* __restrict__ ei_u,
                        const float* __restrict__ c0, const float* __restrict__ c1,
                        const float* __restrict__ W,
                        int* __restrict__ hdr, float* __restrict__ gc,
                        unsigned* __restrict__ deg, float* __restrict__ den) {
  int i = blockIdx.x * THREADS + threadIdx.x;
  if (i < NN) { deg[i] = 0u; den[i] = 0.f; }
  if (blockIdx.x != 0) return;
  __shared__ int sbias;
  int t = threadIdx.x;
  if (t < 64) {
    int odd_nz = 0, even_big = 0;
    for (int k = t; k < 2048; k += 64) {
      unsigned w = ei_u[k];
      if (k & 1) odd_nz += (w != 0u);
      else       even_big += (w >= 1000000u);
    }
    #pragma unroll
    for (int m = 1; m < 64; m <<= 1) {
      odd_nz += __shfl_xor(odd_nz, m, 64);
      even_big += __shfl_xor(even_big, m, 64);
    }
    const unsigned* u0 = (const unsigned*)c0;
    const unsigned* u1 = (const unsigned*)c1;
    unsigned s0 = u0[t] | u0[t + 64], s1 = u1[t] | u1[t + 64];
    #pragma unroll
    for (int m = 1; m < 64; m <<= 1) {
      s0 |= __shfl_xor(s0, m, 64);
      s1 |= __shfl_xor(s1, m, 64);
    }
    if (t == 0) {
      hdr[0] = (odd_nz == 0) ? 1 : ((even_big > 512) ? 2 : 0);
      int b = (s0 == 0u) ? 1 : ((s1 == 0u) ? 0 : 1);
      hdr[1] = b;
      sbias = b;
    }
  }
  __syncthreads();
  const float* bias = sbias ? c0 : c1;
  const float* att  = sbias ? c1 : c0;
  if (t < 128) {
    float g = 0.f;
    for (int o = 0; o < 128; ++o) g = fmaf(att[o], W[o * 128 + t], g);
    gc[t] = g;
    if (t == 0) {
      float c = 0.f;
      for (int o = 0; o < 128; ++o) c = fmaf(att[o], bias[o], c);
      gc[128] = c;
    }
  }
}

// ---- s[i] = bf16(x[i].g + c); optional bf16 copy of x ----------------------
__global__ __launch_bounds__(THREADS) void k_sq(const float* __restrict__ x,
                                                const float* __restrict__ gc,
                                                unsigned short* __restrict__ s,
                                                unsigned short* __restrict__ xb,
                                                int wantxb) {
  int node = blockIdx.x * 4 + (threadIdx.x >> 6);
  if (node >= NN) return;
  int l = threadIdx.x & 63;
  float2 xv = *(const float2*)&x[(size_t)node * 128 + l * 2];
  if (wantxb) {
    unsigned pk = (unsigned)f2bf(xv.x) | ((unsigned)f2bf(xv.y) << 16);
    *(unsigned*)&xb[(size_t)node * 128 + l * 2] = pk;
  }
  float2 gv = *(const float2*)&gc[l * 2];
  float v = xv.x * gv.x + xv.y * gv.y;
  #pragma unroll
  for (int m = 1; m < 64; m <<= 1) v += __shfl_xor(v, m, 64);
  if (l == 0) s[node] = f2bf(v + gc[128]);
}

// ---- edge pass 1: den[src] += exp(alpha); rank[e] = deg[dst]++ -------------
// The deg atomic's return value IS the edge's within-row rank: saved so that
// edge pass 2 needs NO atomics.
__global__ void k_edge1(const void* __restrict__ ei, const int* __restrict__ hdr,
                        const unsigned short* __restrict__ s,
                        unsigned* __restrict__ deg, float* __restrict__ den,
                        unsigned short* __restrict__ rank) {
  int e = blockIdx.x * THREADS + threadIdx.x;
  if (e >= ETT) return;
  int mode = hdr[0];
  if (e < EE) {
    int src = load_edge(ei, mode, e);
    int dst = load_edge(ei, mode, EE + e);
    float a = lrelu(bf2f(s[dst]) + bf2f(s[src]));
    atomicAdd(&den[src], __expf(fminf(a, 60.f)));
    unsigned pos = atomicAdd(&deg[dst], 1u);
    rank[e] = (unsigned short)pos;     // in-degree of random graph << 65536
  } else {
    int i = e - EE;
    float a = lrelu(2.f * bf2f(s[i]));
    atomicAdd(&den[i], __expf(fminf(a, 60.f)));
  }
}

// ---- prefix scan of deg -> rowptr ------------------------------------------
__global__ void k_part(const unsigned* __restrict__ deg, unsigned* __restrict__ part) {
  int i = blockIdx.x * THREADS + threadIdx.x;
  unsigned v = (i < NN) ? deg[i] : 0u;
  #pragma unroll
  for (int m = 1; m < 64; m <<= 1) v += __shfl_xor(v, m, 64);
  __shared__ unsigned sm[4];
  if ((threadIdx.x & 63) == 0) sm[threadIdx.x >> 6] = v;
  __syncthreads();
  if (threadIdx.x == 0) part[blockIdx.x] = sm[0] + sm[1] + sm[2] + sm[3];
}

__global__ void k_scan_top(unsigned* __restrict__ part, int nb) {  // 1 block, 512 thr
  int t = threadIdx.x;
  int lane = t & 63, w = t >> 6;
  unsigned v = (t < nb) ? part[t] : 0u;
  unsigned inc = v;
  #pragma unroll
  for (int d = 1; d < 64; d <<= 1) {
    unsigned o = __shfl_up(inc, d, 64);
    if (lane >= d) inc += o;
  }
  __shared__ unsigned wsum[8];
  if (lane == 63) wsum[w] = inc;
  __syncthreads();
  unsigned off = 0;
  for (int j = 0; j < w; ++j) off += wsum[j];
  if (t < nb) part[t] = inc - v + off;  // exclusive
}

__global__ void k_scan_final(const unsigned* __restrict__ deg, const unsigned* __restrict__ part,
                             unsigned* __restrict__ rowptr) {
  int i = blockIdx.x * THREADS + threadIdx.x;
  int lane = threadIdx.x & 63, w = threadIdx.x >> 6;
  unsigned v = (i < NN) ? deg[i] : 0u;
  unsigned inc = v;
  #pragma unroll
  for (int m = 1; m < 64; m <<= 1) {
    unsigned o = __shfl_up(inc, m, 64);
    if (lane >= m) inc += o;
  }
  __shared__ unsigned wsum[4];
  if (lane == 63) wsum[w] = inc;
  __syncthreads();
  unsigned off = part[blockIdx.x];
  for (int j = 0; j < w; ++j) off += wsum[j];
  if (i < NN) {
    rowptr[i] = inc - v + off;
    if (i == 0) rowptr[NN] = (unsigned)EE;
  }
}

// ---- edge pass 2: ATOMIC-FREE CSR fill via saved ranks ---------------------
__global__ void k_edge2(const void* __restrict__ ei, const int* __restrict__ hdr,
                        const unsigned* __restrict__ rowptr,
                        const unsigned short* __restrict__ rank,
                        unsigned* __restrict__ ent_src) {
  int e = blockIdx.x * THREADS + threadIdx.x;
  if (e >= EE) return;
  int mode = hdr[0];
  int src = load_edge(ei, mode, e);
  int dst = load_edge(ei, mode, EE + e);
  unsigned pos = rowptr[dst] + rank[e];
  if (pos < (unsigned)EE) ent_src[pos] = (unsigned)src;
}

// ---- aggregation: stage (src, w) lane-parallel; unroll-8 row gathers -------
template<int XB>
__global__ __launch_bounds__(THREADS) void k_agg(
    const unsigned* __restrict__ rowptr, const unsigned* __restrict__ ent_src,
    const float* __restrict__ denom, const unsigned short* __restrict__ s,
    unsigned short* __restrict__ sumw_out,
    const float* __restrict__ x, const unsigned short* __restrict__ xb,
    float* __restrict__ z) {
  int v = blockIdx.x * 4 + (threadIdx.x >> 6);
  if (v >= NN) return;
  int l = threadIdx.x & 63;
  unsigned beg = rowptr[v], end = rowptr[v + 1];
  float sv = bf2f(s[v]);
  float wself = __expf(fminf(lrelu(2.f * sv), 60.f)) / denom[v];
  float z0, z1, wsum = wself;
  if (XB) {
    unsigned hv = *(const unsigned*)&xb[((size_t)v << 7) + (l << 1)];
    z0 = wself * bf2f((unsigned short)(hv & 0xFFFFu));
    z1 = wself * bf2f((unsigned short)(hv >> 16));
  } else {
    float2 xv = *(const float2*)&x[((size_t)v << 7) + (l << 1)];
    z0 = wself * xv.x; z1 = wself * xv.y;
  }

  for (unsigned j0 = beg; j0 < end; j0 += 64) {
    unsigned n = end - j0; if (n > 64u) n = 64u;
    unsigned msrc = 0u; float mw = 0.f;
    if (l < (int)n) {                       // lane-parallel stage: src + w
      msrc = ent_src[j0 + l];
      float a = lrelu(sv + bf2f(s[msrc]));
      mw = __expf(fminf(a, 60.f)) / denom[msrc];
    }
    int k = 0;
    for (; k + 8 <= (int)n; k += 8) {       // 8 independent gathers in flight
      unsigned ss[8]; float wv[8];
      #pragma unroll
      for (int q = 0; q < 8; ++q) {
        ss[q] = __shfl(msrc, k + q);
        wv[q] = __shfl(mw, k + q);
      }
      if (XB) {
        unsigned hh[8];
        #pragma unroll
        for (int q = 0; q < 8; ++q)
          hh[q] = *(const unsigned*)&xb[((size_t)ss[q] << 7) + (l << 1)];
        #pragma unroll
        for (int q = 0; q < 8; ++q) {
          z0 = fmaf(wv[q], bf2f((unsigned short)(hh[q] & 0xFFFFu)), z0);
          z1 = fmaf(wv[q], bf2f((unsigned short)(hh[q] >> 16)), z1);
          wsum += wv[q];
        }
      } else {
        float2 xx[8];
        #pragma unroll
        for (int q = 0; q < 8; ++q)
          xx[q] = *(const float2*)&x[((size_t)ss[q] << 7) + (l << 1)];
        #pragma unroll
        for (int q = 0; q < 8; ++q) {
          z0 = fmaf(wv[q], xx[q].x, z0);
          z1 = fmaf(wv[q], xx[q].y, z1);
          wsum += wv[q];
        }
      }
    }
    for (; k < (int)n; ++k) {               // tail
      unsigned sA = __shfl(msrc, k); float wA = __shfl(mw, k);
      if (XB) {
        unsigned hA = *(const unsigned*)&xb[((size_t)sA << 7) + (l << 1)];
        z0 = fmaf(wA, bf2f((unsigned short)(hA & 0xFFFFu)), z0);
        z1 = fmaf(wA, bf2f((unsigned short)(hA >> 16)), z1);
      } else {
        float2 xA = *(const float2*)&x[((size_t)sA << 7) + (l << 1)];
        z0 = fmaf(wA, xA.x, z0); z1 = fmaf(wA, xA.y, z1);
      }
      wsum += wA;
    }
  }
  *(float2*)&z[((size_t)v << 7) + (l << 1)] = make_float2(z0, z1);
  if (l == 0) sumw_out[v] = f2bf(wsum);
}

// ---- out = relu(z @ W^T + sumw*b), f32 in place; W in LDS as bf16 (32KB) ---
__global__ __launch_bounds__(THREADS) void k_out(
    const float* __restrict__ W, const float* __restrict__ c0,
    const float* __restrict__ c1, const int* __restrict__ hdr,
    const unsigned short* __restrict__ sumw, float* __restrict__ zo) {
  const float* bias = hdr[1] ? c0 : c1;
  __shared__ unsigned short wsT[128 * 128];  // W transposed, bf16
  const int t = threadIdx.x;
  #pragma unroll
  for (int i = 0; i < 4; ++i) {
    int idx = i * THREADS + t;
    int o = (idx & 31) * 4;
    int k = (idx >> 5) * 4;
    float4 r0 = *(const float4*)&W[(o + 0) * 128 + k];
    float4 r1 = *(const float4*)&W[(o + 1) * 128 + k];
    float4 r2 = *(const float4*)&W[(o + 2) * 128 + k];
    float4 r3 = *(const float4*)&W[(o + 3) * 128 + k];
    *(ushort4*)&wsT[(k + 0) * 128 + o] = make_ushort4(f2bf(r0.x), f2bf(r1.x), f2bf(r2.x), f2bf(r3.x));
    *(ushort4*)&wsT[(k + 1) * 128 + o] = make_ushort4(f2bf(r0.y), f2bf(r1.y), f2bf(r2.y), f2bf(r3.y));
    *(ushort4*)&wsT[(k + 2) * 128 + o] = make_ushort4(f2bf(r0.z), f2bf(r1.z), f2bf(r2.z), f2bf(r3.z));
    *(ushort4*)&wsT[(k + 3) * 128 + o] = make_ushort4(f2bf(r0.w), f2bf(r1.w), f2bf(r2.w), f2bf(r3.w));
  }
  __syncthreads();

  const int tcol = t & 15;
  const int trow = t >> 4;
  const int row0 = blockIdx.x * 64 + trow * 4;
  int rc[4];
  #pragma unroll
  for (int r = 0; r < 4; ++r) { int rr = row0 + r; rc[r] = rr < NN ? rr : (NN - 1); }

  float acc[4][8];
  #pragma unroll
  for (int r = 0; r < 4; ++r)
    #pragma unroll
    for (int c = 0; c < 8; ++c) acc[r][c] = 0.f;

  for (int k0 = 0; k0 < 128; k0 += 4) {
    float a_[4][4];
    #pragma unroll
    for (int r = 0; r < 4; ++r)
      *(float4*)a_[r] = *(const float4*)&zo[((size_t)rc[r] << 7) + k0];
    #pragma unroll
    for (int kk = 0; kk < 4; ++kk) {
      int k = k0 + kk;
      ushort4 w0u = *(const ushort4*)&wsT[k * 128 + 4 * tcol];
      ushort4 w1u = *(const ushort4*)&wsT[k * 128 + 64 + 4 * tcol];
      #pragma unroll
      for (int r = 0; r < 4; ++r) {
        float av = a_[r][kk];
        acc[r][0] = fmaf(av, bf2f(w0u.x), acc[r][0]);
        acc[r][1] = fmaf(av, bf2f(w0u.y), acc[r][1]);
        acc[r][2] = fmaf(av, bf2f(w0u.z), acc[r][2]);
        acc[r][3] = fmaf(av, bf2f(w0u.w), acc[r][3]);
        acc[r][4] = fmaf(av, bf2f(w1u.x), acc[r][4]);
        acc[r][5] = fmaf(av, bf2f(w1u.y), acc[r][5]);
        acc[r][6] = fmaf(av, bf2f(w1u.z), acc[r][6]);
        acc[r][7] = fmaf(av, bf2f(w1u.w), acc[r][7]);
      }
    }
  }
  __syncthreads();   // all reads of this block's rows done before in-place writes

  float4 b0 = *(const float4*)&bias[4 * tcol];
  float4 b1 = *(const float4*)&bias[64 + 4 * tcol];
  #pragma unroll
  for (int r = 0; r < 4; ++r) {
    int rowg = row0 + r;
    if (rowg >= NN) continue;
    float sw = bf2f(sumw[rowg]);
    float4 o0, o1;
    o0.x = fmaxf(acc[r][0] + sw * b0.x, 0.f);
    o0.y = fmaxf(acc[r][1] + sw * b0.y, 0.f);
    o0.z = fmaxf(acc[r][2] + sw * b0.z, 0.f);
    o0.w = fmaxf(acc[r][3] + sw * b0.w, 0.f);
    o1.x = fmaxf(acc[r][4] + sw * b1.x, 0.f);
    o1.y = fmaxf(acc[r][5] + sw * b1.y, 0.f);
    o1.z = fmaxf(acc[r][6] + sw * b1.z, 0.f);
    o1.w = fmaxf(acc[r][7] + sw * b1.w, 0.f);
    *(float4*)&zo[((size_t)rowg << 7) + 4 * tcol] = o0;
    *(float4*)&zo[((size_t)rowg << 7) + 64 + 4 * tcol] = o1;
  }
}

// ---- edge_index -> f32 at f32 els [12.8M,16M); stomps tier-C scratch -------
__global__ void k_copy_ei_sd(const void* __restrict__ ei, float* __restrict__ out1) {
  __shared__ int smode;
  if (threadIdx.x == 0) {
    int odd_nz = 0, even_big = 0;
    const unsigned* u = (const unsigned*)ei;
    for (int i = 0; i < 128; ++i) {
      unsigned ww = u[i];
      if (i & 1) odd_nz += (ww != 0u);
      else       even_big += (ww >= 1000000u);
    }
    smode = (odd_nz == 0) ? 1 : ((even_big > 32) ? 2 : 0);
  }
  __syncthreads();
  int mode = smode;
  int i2 = (blockIdx.x * THREADS + threadIdx.x) * 2;
  if (i2 >= 2 * EE) return;
  int v0, v1;
  if (mode == 1)      { v0 = ((const int*)ei)[2 * (size_t)i2]; v1 = ((const int*)ei)[2 * (size_t)i2 + 2]; }
  else if (mode == 2) { v0 = (int)((const float*)ei)[i2]; v1 = (int)((const float*)ei)[i2 + 1]; }
  else                { v0 = ((const int*)ei)[i2]; v1 = ((const int*)ei)[i2 + 1]; }
  *(float2*)&out1[i2] = make_float2((float)v0, (float)v1);
}

extern "C" void kernel_launch(void* const* d_in, const int* in_sizes, int n_in,
                              void* d_out, int out_size, void* d_ws, size_t ws_size,
                              hipStream_t stream) {
  // ---- identify inputs by SIZE, fallback positional ----
  const void *px = nullptr, *pei = nullptr, *pW = nullptr, *pc0 = nullptr, *pc1 = nullptr;
  for (int i = 0; i < n_in; ++i) {
    long long sz = in_sizes[i];
    if (sz == (long long)NN * 128 * 4) px = d_in[i];
    else if (sz == (long long)NN * 128 && !px) px = d_in[i];
    else if (sz == 2LL * EE || sz == 4LL * EE || sz == 16LL * EE) pei = d_in[i];
    else if (sz == 128 * 128 || sz == 128 * 128 * 4) pW = d_in[i];
    else if (sz == 128 || sz == 512) { if (!pc0) pc0 = d_in[i]; else if (!pc1) pc1 = d_in[i]; }
  }
  if (!px)  px  = d_in[0];
  if (!pei) pei = d_in[1];
  if (!pW)  pW  = d_in[2];
  if (!pc0) pc0 = d_in[3];
  if (!pc1) pc1 = d_in[4];

  // ---- tier selection ----
  int usexb;
  char* sb;
  if (ws_size >= (size_t)38000000) { sb = (char*)d_ws; usexb = 1; }
  else { sb = (char*)d_out + 51200000u; usexb = 0; }

  size_t off = 0;
  auto take = [&](size_t b) { char* r = sb + off; off = (off + b + 255) & ~(size_t)255; return r; };
  unsigned*       ent_src = (unsigned*)take((size_t)EE * 4);
  unsigned short* rank    = (unsigned short*)take((size_t)EE * 2);
  unsigned*       deg     = (unsigned*)take((size_t)NN * 4);
  float*          den     = (float*)take((size_t)NN * 4);
  unsigned*       rowptr  = (unsigned*)take((size_t)(NN + 1) * 4);
  unsigned short* sbuf    = (unsigned short*)take((size_t)NN * 2);
  unsigned short* sumw    = (unsigned short*)take((size_t)NN * 2);
  unsigned*       part    = (unsigned*)take(2048);
  int*            hdr     = (int*)take(64);
  float*          gc      = (float*)take(129 * 4);
  unsigned short* xb      = usexb ? (unsigned short*)take((size_t)NN * 128 * 2) : nullptr;

  float* out0 = (float*)d_out;                 // [NN,128] f32
  float* out1 = (float*)d_out + EI_F32;        // [2,EE] f32

  const int nb_n  = (NN + THREADS - 1) / THREADS;   // 391
  const int nb_n4 = (NN + 3) / 4;                   // 25000
  const int nb_e  = (ETT + THREADS - 1) / THREADS;  // 6641
  const int nb_e2 = (EE + THREADS - 1) / THREADS;   // 6250

  k_setup<<<nb_n, THREADS, 0, stream>>>((const unsigned*)pei, (const float*)pc0,
                                        (const float*)pc1, (const float*)pW,
                                        hdr, gc, deg, den);
  k_sq<<<nb_n4, THREADS, 0, stream>>>((const float*)px, gc, sbuf, xb, usexb);
  k_edge1<<<nb_e, THREADS, 0, stream>>>(pei, hdr, sbuf, deg, den, rank);
  k_part<<<nb_n, THREADS, 0, stream>>>(deg, part);
  k_scan_top<<<1, 512, 0, stream>>>(part, nb_n);
  k_scan_final<<<nb_n, THREADS, 0, stream>>>(deg, part, rowptr);
  k_edge2<<<nb_e2, THREADS, 0, stream>>>(pei, hdr, rowptr, rank, ent_src);
  if (usexb)
    k_agg<1><<<nb_n4, THREADS, 0, stream>>>(rowptr, ent_src, den, sbuf, sumw,
                                            (const float*)px, xb, out0);
  else
    k_agg<0><<<nb_n4, THREADS, 0, stream>>>(rowptr, ent_src, den, sbuf, sumw,
                                            (const float*)px, nullptr, out0);
  k_out<<<(NN + 63) / 64, THREADS, 0, stream>>>((const float*)pW, (const float*)pc0,
                                                (const float*)pc1, hdr, sumw, out0);
  k_copy_ei_sd<<<nb_e2, THREADS, 0, stream>>>(pei, out1);
}

// Round 16
// 353.834 us; speedup vs baseline: 1.3762x; 1.0190x over previous
//
#include <hip/hip_runtime.h>
#include <hip/hip_bf16.h>

#define THREADS 256
#define NN 100000
#define EE 1600000

// ===== VERIFIED OUTPUT MODEL: d_out is FLOAT32, 16M f32 els =====
//   out : f32 els [0, 12.8M)    ei : f32 els [12.8M, 16M)
#define EI_F32  12800000u
// Scratch tiers:
//   A: ws>=26MB : d_ws, fp8-x copy, ei fused into edge1      (~25MB)
//   C: else     : d_out ei-region, f32 x, separate copy_ei   (~11.3MB)

__device__ __forceinline__ unsigned short f2bf(float f) {
  unsigned u = __float_as_uint(f);
  u = u + 0x7FFFu + ((u >> 16) & 1u);   // RNE
  return (unsigned short)(u >> 16);
}
__device__ __forceinline__ float bf2f(unsigned short v) {
  return __uint_as_float((unsigned)v << 16);
}
__device__ __forceinline__ float lrelu(float a) { return a > 0.f ? a : 0.2f * a; }

// ---- fp8 e4m3fn encode/decode (normals only; |x|<2^-6 flushed to 0) --------
__device__ __forceinline__ unsigned char f2fp8(float f) {
  float a = fabsf(f);
  unsigned sign = (__float_as_uint(f) >> 31) << 7;
  if (a < 0.015625f) return (unsigned char)0;      // flush tiny (abs err <= 2^-6)
  if (a > 448.f) a = 448.f;
  unsigned u = __float_as_uint(a);
  int e = (int)((u >> 23) & 0xFF) - 127;           // [-6, 8]
  unsigned m = u & 0x7FFFFF;
  unsigned t = m + 0x7FFFFu + ((m >> 20) & 1u);    // RNE to 3 bits
  if (t & 0x800000u) { e += 1; t = 0; }
  unsigned m3 = (t >> 20) & 7u;
  if (e > 8) { e = 8; m3 = 6u; }                   // clamp to 448
  return (unsigned char)(sign | ((unsigned)(e + 7) << 3) | m3);
}
__device__ __forceinline__ float fp82f(unsigned b) {
  if ((b & 0x7Fu) == 0u) return 0.f;
  unsigned u = ((b & 0x80u) << 24) | ((((b >> 3) & 0xFu) + 120u) << 23) | ((b & 7u) << 20);
  return __uint_as_float(u);
}

// edge_index element fetch: mode 0=int32, 1=int64(low word), 2=fp32
__device__ __forceinline__ int load_edge(const void* ei, int mode, int idx) {
  int v;
  if (mode == 1)      v = ((const int*)ei)[2 * (size_t)idx];
  else if (mode == 2) v = (int)(((const float*)ei)[idx]);
  else                v = ((const int*)ei)[idx];
  return ((unsigned)v < NN) ? v : 0;
}

// ---- setup: zero deg; block 0: detect + g/c precompute ---------------------
__global__ void k_setup(const unsigned* __restrict__ ei_u,
                        const float* __restrict__ c0, const float* __restrict__ c1,
                        const float* __restrict__ W,
                        int* __restrict__ hdr, float* __restrict__ gc,
                        unsigned* __restrict__ deg) {
  int i = blockIdx.x * THREADS + threadIdx.x;
  if (i < NN) deg[i] = 0u;
  if (blockIdx.x != 0) return;
  __shared__ int sbias;
  int t = threadIdx.x;
  if (t < 64) {
    int odd_nz = 0, even_big = 0;
    for (int k = t; k < 2048; k += 64) {
      unsigned w = ei_u[k];
      if (k & 1) odd_nz += (w != 0u);
      else       even_big += (w >= 1000000u);
    }
    #pragma unroll
    for (int m = 1; m < 64; m <<= 1) {
      odd_nz += __shfl_xor(odd_nz, m, 64);
      even_big += __shfl_xor(even_big, m, 64);
    }
    const unsigned* u0 = (const unsigned*)c0;
    const unsigned* u1 = (const unsigned*)c1;
    unsigned s0 = u0[t] | u0[t + 64], s1 = u1[t] | u1[t + 64];
    #pragma unroll
    for (int m = 1; m < 64; m <<= 1) {
      s0 |= __shfl_xor(s0, m, 64);
      s1 |= __shfl_xor(s1, m, 64);
    }
    if (t == 0) {
      hdr[0] = (odd_nz == 0) ? 1 : ((even_big > 512) ? 2 : 0);
      int b = (s0 == 0u) ? 1 : ((s1 == 0u) ? 0 : 1);
      hdr[1] = b;
      sbias = b;
    }
  }
  __syncthreads();
  const float* bias = sbias ? c0 : c1;
  const float* att  = sbias ? c1 : c0;
  if (t < 128) {
    float g = 0.f;
    for (int o = 0; o < 128; ++o) g = fmaf(att[o], W[o * 128 + t], g);
    gc[t] = g;
    if (t == 0) {
      float c = 0.f;
      for (int o = 0; o < 128; ++o) c = fmaf(att[o], bias[o], c);
      gc[128] = c;
    }
  }
}

// ---- s[i]; den[i] = exp(lrelu(2 s_i)) (self-loop, NON-atomic); fp8 x copy --
__global__ __launch_bounds__(THREADS) void k_sq(const float* __restrict__ x,
                                                const float* __restrict__ gc,
                                                unsigned short* __restrict__ s,
                                                float* __restrict__ den,
                                                unsigned char* __restrict__ xq,
                                                int wantxq) {
  int node = blockIdx.x * 4 + (threadIdx.x >> 6);
  if (node >= NN) return;
  int l = threadIdx.x & 63;
  float2 xv = *(const float2*)&x[(size_t)node * 128 + l * 2];
  if (wantxq) {
    uchar2 pk = make_uchar2(f2fp8(xv.x), f2fp8(xv.y));
    *(uchar2*)&xq[(size_t)node * 128 + l * 2] = pk;
  }
  float2 gv = *(const float2*)&gc[l * 2];
  float v = xv.x * gv.x + xv.y * gv.y;
  #pragma unroll
  for (int m = 1; m < 64; m <<= 1) v += __shfl_xor(v, m, 64);
  if (l == 0) {
    float sv = v + gc[128];
    unsigned short sb = f2bf(sv);
    s[node] = sb;
    float svq = bf2f(sb);                       // match agg's bf16-rounded s
    den[node] = __expf(fminf(lrelu(2.f * svq), 60.f));
  }
}

// ---- edge pass 1: den[src] += exp(alpha); rank[e] = deg[dst]++; [ei out] ---
template<int WRITE_EI>
__global__ void k_edge1(const void* __restrict__ ei, const int* __restrict__ hdr,
                        const unsigned short* __restrict__ s,
                        unsigned* __restrict__ deg, float* __restrict__ den,
                        unsigned short* __restrict__ rank,
                        float* __restrict__ out1) {
  int e = blockIdx.x * THREADS + threadIdx.x;
  if (e >= EE) return;
  int mode = hdr[0];
  int src = load_edge(ei, mode, e);
  int dst = load_edge(ei, mode, EE + e);
  float a = lrelu(bf2f(s[dst]) + bf2f(s[src]));
  atomicAdd(&den[src], __expf(fminf(a, 60.f)));
  unsigned pos = atomicAdd(&deg[dst], 1u);
  rank[e] = (unsigned short)pos;
  if (WRITE_EI) {                       // fused edge_index passthrough (f32)
    out1[e] = (float)src;
    out1[EE + e] = (float)dst;
  }
}

// ---- prefix scan of deg -> rowptr ------------------------------------------
__global__ void k_part(const unsigned* __restrict__ deg, unsigned* __restrict__ part) {
  int i = blockIdx.x * THREADS + threadIdx.x;
  unsigned v = (i < NN) ? deg[i] : 0u;
  #pragma unroll
  for (int m = 1; m < 64; m <<= 1) v += __shfl_xor(v, m, 64);
  __shared__ unsigned sm[4];
  if ((threadIdx.x & 63) == 0) sm[threadIdx.x >> 6] = v;
  __syncthreads();
  if (threadIdx.x == 0) part[blockIdx.x] = sm[0] + sm[1] + sm[2] + sm[3];
}

__global__ void k_scan_top(unsigned* __restrict__ part, int nb) {  // 1 block, 512 thr
  int t = threadIdx.x;
  int lane = t & 63, w = t >> 6;
  unsigned v = (t < nb) ? part[t] : 0u;
  unsigned inc = v;
  #pragma unroll
  for (int d = 1; d < 64; d <<= 1) {
    unsigned o = __shfl_up(inc, d, 64);
    if (lane >= d) inc += o;
  }
  __shared__ unsigned wsum[8];
  if (lane == 63) wsum[w] = inc;
  __syncthreads();
  unsigned off = 0;
  for (int j = 0; j < w; ++j) off += wsum[j];
  if (t < nb) part[t] = inc - v + off;  // exclusive
}

__global__ void k_scan_final(const unsigned* __restrict__ deg, const unsigned* __restrict__ part,
                             unsigned* __restrict__ rowptr) {
  int i = blockIdx.x * THREADS + threadIdx.x;
  int lane = threadIdx.x & 63, w = threadIdx.x >> 6;
  unsigned v = (i < NN) ? deg[i] : 0u;
  unsigned inc = v;
  #pragma unroll
  for (int m = 1; m < 64; m <<= 1) {
    unsigned o = __shfl_up(inc, m, 64);
    if (lane >= m) inc += o;
  }
  __shared__ unsigned wsum[4];
  if (lane == 63) wsum[w] = inc;
  __syncthreads();
  unsigned off = part[blockIdx.x];
  for (int j = 0; j < w; ++j) off += wsum[j];
  if (i < NN) {
    rowptr[i] = inc - v + off;
    if (i == 0) rowptr[NN] = (unsigned)EE;
  }
}

// ---- edge pass 2: ATOMIC-FREE CSR fill via saved ranks ---------------------
__global__ void k_edge2(const void* __restrict__ ei, const int* __restrict__ hdr,
                        const unsigned* __restrict__ rowptr,
                        const unsigned short* __restrict__ rank,
                        unsigned* __restrict__ ent_src) {
  int e = blockIdx.x * THREADS + threadIdx.x;
  if (e >= EE) return;
  int mode = hdr[0];
  int src = load_edge(ei, mode, e);
  int dst = load_edge(ei, mode, EE + e);
  unsigned pos = rowptr[dst] + rank[e];
  if (pos < (unsigned)EE) ent_src[pos] = (unsigned)src;
}

// ---- aggregation: stage (src, w) lane-parallel; unroll-8 row gathers -------
// XB=1: fp8 rows (128B/row, half the random-line traffic).
template<int XB>
__global__ __launch_bounds__(THREADS) void k_agg(
    const unsigned* __restrict__ rowptr, const unsigned* __restrict__ ent_src,
    const float* __restrict__ denom, const unsigned short* __restrict__ s,
    unsigned short* __restrict__ sumw_out,
    const float* __restrict__ x, const unsigned char* __restrict__ xq,
    float* __restrict__ z) {
  int v = blockIdx.x * 4 + (threadIdx.x >> 6);
  if (v >= NN) return;
  int l = threadIdx.x & 63;
  unsigned beg = rowptr[v], end = rowptr[v + 1];
  float sv = bf2f(s[v]);
  float wself = __expf(fminf(lrelu(2.f * sv), 60.f)) / denom[v];
  float z0, z1, wsum = wself;
  {
    float2 xv = *(const float2*)&x[((size_t)v << 7) + (l << 1)];  // exact self term
    z0 = wself * xv.x; z1 = wself * xv.y;
  }

  for (unsigned j0 = beg; j0 < end; j0 += 64) {
    unsigned n = end - j0; if (n > 64u) n = 64u;
    unsigned msrc = 0u; float mw = 0.f;
    if (l < (int)n) {                       // lane-parallel stage: src + w
      msrc = ent_src[j0 + l];
      float a = lrelu(sv + bf2f(s[msrc]));
      mw = __expf(fminf(a, 60.f)) / denom[msrc];
    }
    int k = 0;
    for (; k + 8 <= (int)n; k += 8) {       // 8 independent gathers in flight
      unsigned ss[8]; float wv[8];
      #pragma unroll
      for (int q = 0; q < 8; ++q) {
        ss[q] = __shfl(msrc, k + q);
        wv[q] = __shfl(mw, k + q);
      }
      if (XB) {
        unsigned short hh[8];
        #pragma unroll
        for (int q = 0; q < 8; ++q)
          hh[q] = *(const unsigned short*)&xq[((size_t)ss[q] << 7) + (l << 1)];
        #pragma unroll
        for (int q = 0; q < 8; ++q) {
          z0 = fmaf(wv[q], fp82f(hh[q] & 0xFFu), z0);
          z1 = fmaf(wv[q], fp82f(hh[q] >> 8), z1);
          wsum += wv[q];
        }
      } else {
        float2 xx[8];
        #pragma unroll
        for (int q = 0; q < 8; ++q)
          xx[q] = *(const float2*)&x[((size_t)ss[q] << 7) + (l << 1)];
        #pragma unroll
        for (int q = 0; q < 8; ++q) {
          z0 = fmaf(wv[q], xx[q].x, z0);
          z1 = fmaf(wv[q], xx[q].y, z1);
          wsum += wv[q];
        }
      }
    }
    for (; k < (int)n; ++k) {               // tail
      unsigned sA = __shfl(msrc, k); float wA = __shfl(mw, k);
      if (XB) {
        unsigned short hA = *(const unsigned short*)&xq[((size_t)sA << 7) + (l << 1)];
        z0 = fmaf(wA, fp82f(hA & 0xFFu), z0);
        z1 = fmaf(wA, fp82f(hA >> 8), z1);
      } else {
        float2 xA = *(const float2*)&x[((size_t)sA << 7) + (l << 1)];
        z0 = fmaf(wA, xA.x, z0); z1 = fmaf(wA, xA.y, z1);
      }
      wsum += wA;
    }
  }
  *(float2*)&z[((size_t)v << 7) + (l << 1)] = make_float2(z0, z1);
  if (l == 0) sumw_out[v] = f2bf(wsum);
}

// ---- out = relu(z @ W^T + sumw*b), f32 in place; W in LDS as bf16 (32KB) ---
__global__ __launch_bounds__(THREADS) void k_out(
    const float* __restrict__ W, const float* __restrict__ c0,
    const float* __restrict__ c1, const int* __restrict__ hdr,
    const unsigned short* __restrict__ sumw, float* __restrict__ zo) {
  const float* bias = hdr[1] ? c0 : c1;
  __shared__ unsigned short wsT[128 * 128];  // W transposed, bf16
  const int t = threadIdx.x;
  #pragma unroll
  for (int i = 0; i < 4; ++i) {
    int idx = i * THREADS + t;
    int o = (idx & 31) * 4;
    int k = (idx >> 5) * 4;
    float4 r0 = *(const float4*)&W[(o + 0) * 128 + k];
    float4 r1 = *(const float4*)&W[(o + 1) * 128 + k];
    float4 r2 = *(const float4*)&W[(o + 2) * 128 + k];
    float4 r3 = *(const float4*)&W[(o + 3) * 128 + k];
    *(ushort4*)&wsT[(k + 0) * 128 + o] = make_ushort4(f2bf(r0.x), f2bf(r1.x), f2bf(r2.x), f2bf(r3.x));
    *(ushort4*)&wsT[(k + 1) * 128 + o] = make_ushort4(f2bf(r0.y), f2bf(r1.y), f2bf(r2.y), f2bf(r3.y));
    *(ushort4*)&wsT[(k + 2) * 128 + o] = make_ushort4(f2bf(r0.z), f2bf(r1.z), f2bf(r2.z), f2bf(r3.z));
    *(ushort4*)&wsT[(k + 3) * 128 + o] = make_ushort4(f2bf(r0.w), f2bf(r1.w), f2bf(r2.w), f2bf(r3.w));
  }
  __syncthreads();

  const int tcol = t & 15;
  const int trow = t >> 4;
  const int row0 = blockIdx.x * 64 + trow * 4;
  int rc[4];
  #pragma unroll
  for (int r = 0; r < 4; ++r) { int rr = row0 + r; rc[r] = rr < NN ? rr : (NN - 1); }

  float acc[4][8];
  #pragma unroll
  for (int r = 0; r < 4; ++r)
    #pragma unroll
    for (int c = 0; c < 8; ++c) acc[r][c] = 0.f;

  for (int k0 = 0; k0 < 128; k0 += 4) {
    float a_[4][4];
    #pragma unroll
    for (int r = 0; r < 4; ++r)
      *(float4*)a_[r] = *(const float4*)&zo[((size_t)rc[r] << 7) + k0];
    #pragma unroll
    for (int kk = 0; kk < 4; ++kk) {
      int k = k0 + kk;
      ushort4 w0u = *(const ushort4*)&wsT[k * 128 + 4 * tcol];
      ushort4 w1u = *(const ushort4*)&wsT[k * 128 + 64 + 4 * tcol];
      #pragma unroll
      for (int r = 0; r < 4; ++r) {
        float av = a_[r][kk];
        acc[r][0] = fmaf(av, bf2f(w0u.x), acc[r][0]);
        acc[r][1] = fmaf(av, bf2f(w0u.y), acc[r][1]);
        acc[r][2] = fmaf(av, bf2f(w0u.z), acc[r][2]);
        acc[r][3] = fmaf(av, bf2f(w0u.w), acc[r][3]);
        acc[r][4] = fmaf(av, bf2f(w1u.x), acc[r][4]);
        acc[r][5] = fmaf(av, bf2f(w1u.y), acc[r][5]);
        acc[r][6] = fmaf(av, bf2f(w1u.z), acc[r][6]);
        acc[r][7] = fmaf(av, bf2f(w1u.w), acc[r][7]);
      }
    }
  }
  __syncthreads();   // all reads of this block's rows done before in-place writes

  float4 b0 = *(const float4*)&bias[4 * tcol];
  float4 b1 = *(const float4*)&bias[64 + 4 * tcol];
  #pragma unroll
  for (int r = 0; r < 4; ++r) {
    int rowg = row0 + r;
    if (rowg >= NN) continue;
    float sw = bf2f(sumw[rowg]);
    float4 o0, o1;
    o0.x = fmaxf(acc[r][0] + sw * b0.x, 0.f);
    o0.y = fmaxf(acc[r][1] + sw * b0.y, 0.f);
    o0.z = fmaxf(acc[r][2] + sw * b0.z, 0.f);
    o0.w = fmaxf(acc[r][3] + sw * b0.w, 0.f);
    o1.x = fmaxf(acc[r][4] + sw * b1.x, 0.f);
    o1.y = fmaxf(acc[r][5] + sw * b1.y, 0.f);
    o1.z = fmaxf(acc[r][6] + sw * b1.z, 0.f);
    o1.w = fmaxf(acc[r][7] + sw * b1.w, 0.f);
    *(float4*)&zo[((size_t)rowg << 7) + 4 * tcol] = o0;
    *(float4*)&zo[((size_t)rowg << 7) + 64 + 4 * tcol] = o1;
  }
}

// ---- standalone edge_index copy (tier-C only; stomps tier-C scratch) -------
__global__ void k_copy_ei_sd(const void* __restrict__ ei, float* __restrict__ out1) {
  __shared__ int smode;
  if (threadIdx.x == 0) {
    int odd_nz = 0, even_big = 0;
    const unsigned* u = (const unsigned*)ei;
    for (int i = 0; i < 128; ++i) {
      unsigned ww = u[i];
      if (i & 1) odd_nz += (ww != 0u);
      else       even_big += (ww >= 1000000u);
    }
    smode = (odd_nz == 0) ? 1 : ((even_big > 32) ? 2 : 0);
  }
  __syncthreads();
  int mode = smode;
  int i2 = (blockIdx.x * THREADS + threadIdx.x) * 2;
  if (i2 >= 2 * EE) return;
  int v0, v1;
  if (mode == 1)      { v0 = ((const int*)ei)[2 * (size_t)i2]; v1 = ((const int*)ei)[2 * (size_t)i2 + 2]; }
  else if (mode == 2) { v0 = (int)((const float*)ei)[i2]; v1 = (int)((const float*)ei)[i2 + 1]; }
  else                { v0 = ((const int*)ei)[i2]; v1 = ((const int*)ei)[i2 + 1]; }
  *(float2*)&out1[i2] = make_float2((float)v0, (float)v1);
}

extern "C" void kernel_launch(void* const* d_in, const int* in_sizes, int n_in,
                              void* d_out, int out_size, void* d_ws, size_t ws_size,
                              hipStream_t stream) {
  // ---- identify inputs by SIZE, fallback positional ----
  const void *px = nullptr, *pei = nullptr, *pW = nullptr, *pc0 = nullptr, *pc1 = nullptr;
  for (int i = 0; i < n_in; ++i) {
    long long sz = in_sizes[i];
    if (sz == (long long)NN * 128 * 4) px = d_in[i];
    else if (sz == (long long)NN * 128 && !px) px = d_in[i];
    else if (sz == 2LL * EE || sz == 4LL * EE || sz == 16LL * EE) pei = d_in[i];
    else if (sz == 128 * 128 || sz == 128 * 128 * 4) pW = d_in[i];
    else if (sz == 128 || sz == 512) { if (!pc0) pc0 = d_in[i]; else if (!pc1) pc1 = d_in[i]; }
  }
  if (!px)  px  = d_in[0];
  if (!pei) pei = d_in[1];
  if (!pW)  pW  = d_in[2];
  if (!pc0) pc0 = d_in[3];
  if (!pc1) pc1 = d_in[4];

  // ---- tier selection ----
  int usexq;
  char* sb;
  if (ws_size >= (size_t)26000000) { sb = (char*)d_ws; usexq = 1; }
  else { sb = (char*)d_out + 51200000u; usexq = 0; }

  size_t off = 0;
  auto take = [&](size_t b) { char* r = sb + off; off = (off + b + 255) & ~(size_t)255; return r; };
  unsigned*       ent_src = (unsigned*)take((size_t)EE * 4);
  unsigned short* rank    = (unsigned short*)take((size_t)EE * 2);
  unsigned*       deg     = (unsigned*)take((size_t)NN * 4);
  float*          den     = (float*)take((size_t)NN * 4);
  unsigned*       rowptr  = (unsigned*)take((size_t)(NN + 1) * 4);
  unsigned short* sbuf    = (unsigned short*)take((size_t)NN * 2);
  unsigned short* sumw    = (unsigned short*)take((size_t)NN * 2);
  unsigned*       part    = (unsigned*)take(2048);
  int*            hdr     = (int*)take(64);
  float*          gc      = (float*)take(129 * 4);
  unsigned char*  xq      = usexq ? (unsigned char*)take((size_t)NN * 128) : nullptr;

  float* out0 = (float*)d_out;                 // [NN,128] f32
  float* out1 = (float*)d_out + EI_F32;        // [2,EE] f32

  const int nb_n  = (NN + THREADS - 1) / THREADS;   // 391
  const int nb_n4 = (NN + 3) / 4;                   // 25000
  const int nb_e2 = (EE + THREADS - 1) / THREADS;   // 6250

  k_setup<<<nb_n, THREADS, 0, stream>>>((const unsigned*)pei, (const float*)pc0,
                                        (const float*)pc1, (const float*)pW,
                                        hdr, gc, deg);
  k_sq<<<nb_n4, THREADS, 0, stream>>>((const float*)px, gc, sbuf, den, xq, usexq);
  if (usexq)
    k_edge1<1><<<nb_e2, THREADS, 0, stream>>>(pei, hdr, sbuf, deg, den, rank, out1);
  else
    k_edge1<0><<<nb_e2, THREADS, 0, stream>>>(pei, hdr, sbuf, deg, den, rank, out1);
  k_part<<<nb_n, THREADS, 0, stream>>>(deg, part);
  k_scan_top<<<1, 512, 0, stream>>>(part, nb_n);
  k_scan_final<<<nb_n, THREADS, 0, stream>>>(deg, part, rowptr);
  k_edge2<<<nb_e2, THREADS, 0, stream>>>(pei, hdr, rowptr, rank, ent_src);
  if (usexq)
    k_agg<1><<<nb_n4, THREADS, 0, stream>>>(rowptr, ent_src, den, sbuf, sumw,
                                            (const float*)px, xq, out0);
  else
    k_agg<0><<<nb_n4, THREADS, 0, stream>>>(rowptr, ent_src, den, sbuf, sumw,
                                            (const float*)px, nullptr, out0);
  k_out<<<(NN + 63) / 64, THREADS, 0, stream>>>((const float*)pW, (const float*)pc0,
                                                (const float*)pc1, hdr, sumw, out0);
  if (!usexq)
    k_copy_ei_sd<<<nb_e2, THREADS, 0, stream>>>(pei, out1);
}